// Round 6
// baseline (24182.896 us; speedup 1.0000x reference)
//
#include <hip/hip_runtime.h>
#include <hip/hip_fp16.h>
#include <math.h>

// ---------------------------------------------------------------------------
// SonataCodec forward. Round 6: fp32-GRID RVQ.
// Rounds 2-5: every fp64 variant (2 encoders x 3 RVQs) gives bit-identical
// codes absmax 681.0 => reference is fp32; passing requires sharing fp32's
// quantization grid in d2 (|zp|^2 ~ 10 => ulp ~ 1e-6 dominates all op-order
// noise ~1e-9). This build: RVQ entirely fp32 with the reference's exact
// formula structure (zp proj, zq_st = zp+(zq-zp), d2=(zp2-2dot)+cn2, residual
// update for all 8 books, z_q = z - R_final). Encoder fast-fp64 (proven
// equivalent to naive across r3-r5). Decoder unchanged (audio passes).
// ---------------------------------------------------------------------------

#define T_RVQ 249
#define ROWS  (64*249)     // 15936
#define NB    8
#define NCODE 1024

static inline int cdiv(int a, int b){ return (a+b-1)/b; }

// ---------------- pack kernels ----------------
__global__ void pack_w_conv(const float* __restrict__ w, float* __restrict__ wp,
                            int COUT, int CIN, int K){
  int i = blockIdx.x*256 + threadIdx.x;
  int tot = COUT*CIN*K;
  if (i >= tot) return;
  int co = i / (CIN*K); int r = i - co*(CIN*K);
  wp[(long)r*COUT + co] = w[i];
}
__global__ void pack_w_convT(const float* __restrict__ w, float* __restrict__ wp,
                             int CIN, int COUT, int K){
  int i = blockIdx.x*256 + threadIdx.x;
  int tot = CIN*COUT*K;
  if (i >= tot) return;
  int ci = i / (COUT*K); int r = i - ci*(COUT*K);
  int co = r / K; int j = r - co*K;
  wp[(long)(ci*K + j)*COUT + co] = w[i];
}
// fp32 per-code squared norms (sequential, reference-scale grid)
__global__ void prep_cn2f(const float* __restrict__ cbs, float* __restrict__ cn2){
  int i = blockIdx.x*256 + threadIdx.x;  // 8192 codes
  if (i >= NB*NCODE) return;
  const float* c = cbs + (long)i*128;
  float s = 0.f;
  for (int d=0; d<128; d++) s += c[d]*c[d];
  cn2[i] = s;
}
__global__ void zero_loss(double* p){ p[0] = 0.0; }

// ---------------- fused E0+E1 (all fp64, fp64 out) -------------------------
__global__ __launch_bounds__(256) void conv_e0e1(
    const float* __restrict__ audio,   // [32][120000] (offset view)
    const float* __restrict__ w0,      // [64][16]
    const float* __restrict__ b0v, const float* __restrict__ a0v,
    const float* __restrict__ wp1,     // packed [64*10][128]
    const float* __restrict__ b1v, const float* __restrict__ a1v,
    double* __restrict__ out)          // [32][128][2999] fp64
{
  constexpr int WIDTH = 63*5 + 10;        // 325 E0 positions
  constexpr int AW    = (WIDTH-1)*8 + 16; // 2608 audio samples
  __shared__ double aud_s[AW];
  __shared__ double w0_s[64][16];
  __shared__ double b0_s[64], a0_s[64], i0_s[64];
  __shared__ double xs[4][WIDTH];
  __shared__ double ws[40][64];
  const int tid  = threadIdx.x;
  const int lo_t = tid & 15;
  const int co_t = tid >> 4;
  const int b    = blockIdx.z;
  const int co0  = blockIdx.y*64;
  const int lo0  = blockIdx.x*64;
  const int g0   = lo0*5 - 2;
  const long aud0 = (long)g0*8 - 4;
  for (int idx=tid; idx<AW; idx+=256){
    long s = aud0 + idx;
    aud_s[idx] = (s>=0 && s<120000) ? (double)audio[(long)b*120000 + s] : 0.0;
  }
  for (int idx=tid; idx<1024; idx+=256)
    w0_s[idx>>4][idx&15] = (double)w0[idx];
  if (tid < 64){
    b0_s[tid] = (double)b0v[tid];
    double a = (double)a0v[tid];
    a0_s[tid] = a; i0_s[tid] = 1.0/a;
  }
  double acc[4][4];
  #pragma unroll
  for (int c=0;c<4;c++){ acc[c][0]=0; acc[c][1]=0; acc[c][2]=0; acc[c][3]=0; }
  for (int ci0=0; ci0<64; ci0+=4){
    __syncthreads();
    for (int idx=tid; idx<4*WIDTH; idx+=256){
      int cich = idx / WIDTH, p = idx - cich*WIDTH;
      int ci = ci0 + cich;
      double v = b0_s[ci];
      #pragma unroll
      for (int j=0;j<16;j++) v += w0_s[ci][j]*aud_s[p*8 + j];
      double sn = sin(a0_s[ci]*v);
      double e0 = v + i0_s[ci]*sn*sn;
      int g = g0 + p;
      xs[cich][p] = (g>=0 && g<15000) ? e0 : 0.0;
    }
    for (int idx=tid; idx<40*64; idx+=256){
      int col = idx & 63, r = idx >> 6;
      ws[r][col] = (double)wp1[(long)(ci0*10 + r)*128 + co0 + col];
    }
    __syncthreads();
    for (int cich=0; cich<4; cich++){
      #pragma unroll
      for (int j=0;j<10;j++){
        double wv0 = ws[cich*10+j][co_t     ];
        double wv1 = ws[cich*10+j][co_t + 16];
        double wv2 = ws[cich*10+j][co_t + 32];
        double wv3 = ws[cich*10+j][co_t + 48];
        #pragma unroll
        for (int m=0;m<4;m++){
          double xv = xs[cich][(lo_t + 16*m)*5 + j];
          acc[0][m] += wv0*xv; acc[1][m] += wv1*xv;
          acc[2][m] += wv2*xv; acc[3][m] += wv3*xv;
        }
      }
    }
  }
  #pragma unroll
  for (int c=0;c<4;c++){
    int co = co0 + co_t + 16*c;
    double bv  = (double)b1v[co];
    double a   = (double)a1v[co];
    double inv = 1.0/a;
    #pragma unroll
    for (int m=0;m<4;m++){
      int lo = lo0 + lo_t + 16*m;
      if (lo < 2999){
        double v = acc[c][m] + bv;
        double sn = sin(a*v);
        v = v + inv*sn*sn;
        out[((long)b*128 + co)*2999 + lo] = v;
      }
    }
  }
}

// ---------------- encoder conv E2/E3 (fp64 in, fp64 out) -------------------
template<int CIN,int COUT,int K,int S,int PAD,int CICH>
__global__ __launch_bounds__(256) void conv_enc(
    const double* __restrict__ x, const float* __restrict__ wp,
    const float* __restrict__ bias, const float* __restrict__ alpha,
    double* __restrict__ out, int Lin, int Lout)
{
  constexpr int WIDTH = 63*S + K;
  __shared__ double xs[CICH][WIDTH];
  __shared__ double ws[CICH*K][64];
  const int tid  = threadIdx.x;
  const int lo_t = tid & 15;
  const int co_t = tid >> 4;
  const int b    = blockIdx.z;
  const int co0  = blockIdx.y*64;
  const int lo0  = blockIdx.x*64;
  const int x0   = lo0*S - PAD;
  const long xb  = (long)b*CIN*Lin;
  double acc[4][4];
  #pragma unroll
  for (int c=0;c<4;c++){ acc[c][0]=0; acc[c][1]=0; acc[c][2]=0; acc[c][3]=0; }
  for (int ci0=0; ci0<CIN; ci0+=CICH){
    __syncthreads();
    for (int idx=tid; idx<CICH*WIDTH; idx+=256){
      int ci = idx / WIDTH, p = idx - ci*WIDTH;
      int g = x0 + p;
      xs[ci][p] = (g>=0 && g<Lin) ? x[xb + (long)(ci0+ci)*Lin + g] : 0.0;
    }
    for (int idx=tid; idx<CICH*K*64; idx+=256){
      int col = idx & 63, r = idx >> 6;
      ws[r][col] = (double)wp[(long)(ci0*K + r)*COUT + co0 + col];
    }
    __syncthreads();
    for (int ci=0; ci<CICH; ci++){
      #pragma unroll
      for (int j=0;j<K;j++){
        double w0 = ws[ci*K+j][co_t     ];
        double w1 = ws[ci*K+j][co_t + 16];
        double w2 = ws[ci*K+j][co_t + 32];
        double w3 = ws[ci*K+j][co_t + 48];
        #pragma unroll
        for (int m=0;m<4;m++){
          double xv = xs[ci][(lo_t + 16*m)*S + j];
          acc[0][m] += w0*xv; acc[1][m] += w1*xv;
          acc[2][m] += w2*xv; acc[3][m] += w3*xv;
        }
      }
    }
  }
  #pragma unroll
  for (int c=0;c<4;c++){
    int co = co0 + co_t + 16*c;
    double bv  = (double)bias[co];
    double a   = (double)alpha[co];
    double inv = 1.0/a;
    #pragma unroll
    for (int m=0;m<4;m++){
      int lo = lo0 + lo_t + 16*m;
      if (lo < Lout){
        double v = acc[c][m] + bv;
        double sn = sin(a*v);
        v = v + inv*sn*sn;
        out[((long)b*COUT + co)*Lout + lo] = v;
      }
    }
  }
}

// ---------------- decoder transposed conv (fp32), phase-decomposed ---------
template<int CIN,int COUT,int K,int S,int PAD,int CICH,typename OUTT>
__global__ __launch_bounds__(256) void convT_dec(
    const float* __restrict__ x, const float* __restrict__ wp,
    const float* __restrict__ bias, const float* __restrict__ alpha,
    OUTT* __restrict__ out, int Lin, int Lout)
{
  __shared__ float xs[CICH][66];
  __shared__ float ws[CICH][2][64];
  const int tid  = threadIdx.x;
  const int t_t  = tid & 15;
  const int co_t = tid >> 4;
  const int bx   = blockIdx.x;
  const int r    = bx % S;
  const int t10  = (bx / S) * 64;
  const int b    = blockIdx.z;
  const int co0  = blockIdx.y*64;
  float acc[4][4];
  #pragma unroll
  for (int c=0;c<4;c++){ acc[c][0]=0; acc[c][1]=0; acc[c][2]=0; acc[c][3]=0; }
  for (int ci0=0; ci0<CIN; ci0+=CICH){
    __syncthreads();
    for (int idx=tid; idx<CICH*65; idx+=256){
      int ci = idx / 65, p = idx - ci*65;
      int g = t10 - 1 + p;
      xs[ci][p] = (g>=0 && g<Lin) ? x[((long)b*CIN + ci0+ci)*Lin + g] : 0.f;
    }
    for (int idx=tid; idx<CICH*2*64; idx+=256){
      int col = idx & 63, q = idx >> 6;
      int ci = q >> 1, tap = q & 1;
      ws[ci][tap][col] = wp[(long)((ci0+ci)*K + r + tap*S)*COUT + co0 + col];
    }
    __syncthreads();
    for (int ci=0; ci<CICH; ci++){
      float w0[4], w1[4];
      #pragma unroll
      for (int c=0;c<4;c++){ w0[c]=ws[ci][0][co_t+16*c]; w1[c]=ws[ci][1][co_t+16*c]; }
      #pragma unroll
      for (int m=0;m<4;m++){
        float xa = xs[ci][t_t + 16*m + 1];   // x[t1]
        float xp = xs[ci][t_t + 16*m];       // x[t1-1]
        #pragma unroll
        for (int c=0;c<4;c++) acc[c][m] += w0[c]*xa + w1[c]*xp;
      }
    }
  }
  #pragma unroll
  for (int c=0;c<4;c++){
    int co = co0 + co_t + 16*c;
    float bv  = bias[co];
    float a   = alpha[co];
    float inv = 1.f/a;
    #pragma unroll
    for (int m=0;m<4;m++){
      int t1 = t10 + t_t + 16*m;
      int lo = t1*S + r - PAD;
      if (lo >= 0 && lo < Lout){
        float v = acc[c][m] + bv;
        float sn = sinf(a*v);
        v = v + inv*sn*sn;
        out[((long)b*COUT + co)*Lout + lo] = OUTT(v);
      }
    }
  }
}

// ---------------- final decoder layer (CIN=64 -> CO=1, k=16, s=8, tanh) ----
__global__ __launch_bounds__(256) void convT_last(
    const __half* __restrict__ x,  // [64][64][14961] fp16
    const float* __restrict__ w,   // [64][1][16]
    const float* __restrict__ bias,
    float* __restrict__ out)       // [64][119688]
{
  constexpr int LIN = 14961, LOUT = 119688, CIN = 64;
  __shared__ __align__(16) float xs[8][1028];
  __shared__ float ws[8][16];
  const int tid = threadIdx.x;
  const int b   = blockIdx.z;
  const int t10 = blockIdx.x*1024;
  float acc[4][8];
  #pragma unroll
  for (int u=0;u<4;u++) for (int rr=0;rr<8;rr++) acc[u][rr]=0.f;
  for (int ci0=0; ci0<CIN; ci0+=8){
    __syncthreads();
    for (int idx=tid; idx<8*1025; idx+=256){
      int ci = idx / 1025, p = idx - ci*1025;
      int g = t10 - 1 + p;
      xs[ci][p] = (g>=0 && g<LIN) ? __half2float(x[((long)b*CIN + ci0+ci)*LIN + g]) : 0.f;
    }
    if (tid < 128){
      int ci = tid >> 4, j = tid & 15;
      ws[ci][j] = w[(ci0+ci)*16 + j];
    }
    __syncthreads();
    #pragma unroll 2
    for (int ci=0; ci<8; ci++){
      float4 xv = *(const float4*)&xs[ci][tid*4];
      float  xe = xs[ci][tid*4 + 4];
      float xb_[5] = {xv.x, xv.y, xv.z, xv.w, xe};
      #pragma unroll
      for (int u=0;u<4;u++){
        float xprev = xb_[u];
        float xcur  = xb_[u+1];
        #pragma unroll
        for (int rr=0; rr<8; rr++)
          acc[u][rr] += ws[ci][rr]*xcur + ws[ci][rr+8]*xprev;
      }
    }
  }
  float bv = bias[0];
  #pragma unroll
  for (int u=0;u<4;u++){
    int t1 = t10 + tid*4 + u;
    #pragma unroll
    for (int rr=0;rr<8;rr++){
      int lo = t1*8 + rr - 4;
      if (lo >= 0 && lo < LOUT)
        out[(long)b*LOUT + lo] = tanhf(acc[u][rr] + bv);
    }
  }
}

// ======================= fp32 RVQ (reference-structured) ===================
// R[row][c] = (float)z[b][c][t]   (row = b*249 + t)
__global__ void nv_transpose_f(const double* __restrict__ z, float* __restrict__ R){
  long i = (long)blockIdx.x*256 + threadIdx.x;     // ROWS*512
  if (i >= (long)ROWS*512) return;
  int row = (int)(i >> 9); int c = (int)(i & 511);
  int b = row / T_RVQ, t = row - b*T_RVQ;
  R[i] = (float)z[((long)b*512 + c)*T_RVQ + t];
}

// zp[row][d] = (sum_c R[row][c]*pin_w[d][c]) + pin_b[d]    (all fp32)
__global__ __launch_bounds__(128) void nv_proj_f(
    const float* __restrict__ R, const float* __restrict__ pin_w,
    const float* __restrict__ pin_b, float* __restrict__ zp)
{
  int row = blockIdx.x; int d = threadIdx.x;
  const float* r = R + (long)row*512;
  const float* w = pin_w + (long)d*512;
  float s = 0.f;
  for (int c=0;c<512;c++) s += r[c]*w[c];
  zp[(long)row*128 + d] = s + pin_b[d];
}

// d2 = (zp2 - 2*dot) + cn2, all fp32 (shared quantization grid with np ref).
// 32 rows/block; 8 threads/row over ascending code blocks -> first-min.
__global__ __launch_bounds__(256) void nv_dist_f(
    const float* __restrict__ zp, const float* __restrict__ cb,
    const float* __restrict__ cn2, float* __restrict__ codes_out,
    int* __restrict__ codes_int, double* __restrict__ loss_acc, int book)
{
  __shared__ float zp_l[32][129];
  __shared__ float zp2_l[32];
  __shared__ float cb_l[8][128];
  __shared__ float sv[32][8];
  __shared__ int   si[32][8];
  __shared__ double ls[32];
  const int tid  = threadIdx.x;
  const int row0 = blockIdx.x*32;
  for (int idx=tid; idx<32*128; idx+=256){
    int r = idx >> 7, d = idx & 127;
    zp_l[r][d] = zp[(long)(row0+r)*128 + d];
  }
  __syncthreads();
  if (tid < 32){
    float s2 = 0.f;
    for (int d=0; d<128; d++) s2 += zp_l[tid][d]*zp_l[tid][d];
    zp2_l[tid] = s2;
  }
  const int r = tid & 31, g = tid >> 5;
  float best = 3.4e38f; int bi = 0;
  for (int k=0;k<128;k++){
    __syncthreads();
    for (int idx=tid; idx<1024; idx+=256){
      int gg = idx >> 7, d = idx & 127;
      cb_l[gg][d] = cb[(long)(gg*128 + k)*128 + d];
    }
    __syncthreads();
    float dot = 0.f;
    #pragma unroll 4
    for (int d=0; d<128; d++) dot += zp_l[r][d]*cb_l[g][d];
    int n = g*128 + k;
    float dist = (zp2_l[r] - 2.0f*dot) + cn2[n];
    if (dist < best){ best = dist; bi = n; }
  }
  sv[r][g] = best; si[r][g] = bi;
  __syncthreads();
  if (g == 0){
    float b2 = sv[r][0]; int i2 = si[r][0];
    for (int gg=1; gg<8; gg++)
      if (sv[r][gg] < b2){ b2 = sv[r][gg]; i2 = si[r][gg]; }
    int row = row0 + r;
    int bb = row / T_RVQ, t = row - bb*T_RVQ;
    codes_out[bb*(NB*T_RVQ) + book*T_RVQ + t] = (float)i2;
    codes_int[(long)row*NB + book] = i2;
    ls[r] = (double)b2;     // = |zq - zp|^2 summed over d (loss term)
  }
  __syncthreads();
  if (tid == 0){
    double s = 0.0;
    for (int rr=0;rr<32;rr++) s += ls[rr];
    atomicAdd(loss_acc, s);
  }
}

// R[row][c] -= (sum_d zq_st[d]*pout_w[c][d]) + pout_b[c], zq_st = zp+(zq-zp)
__global__ __launch_bounds__(256) void nv_update_f(
    float* __restrict__ R, const float* __restrict__ cb,
    const float* __restrict__ zp, const float* __restrict__ pout_w,
    const float* __restrict__ pout_b, const int* __restrict__ codes_int,
    int book)
{
  __shared__ float st_l[128];
  const int row = blockIdx.x; const int tid = threadIdx.x;
  int code = codes_int[(long)row*NB + book];
  if (tid < 128){
    float zpv = zp[(long)row*128 + tid];
    float zqv = cb[(long)code*128 + tid];
    st_l[tid] = zpv + (zqv - zpv);      // fp32 zq_st (forward == zq +- ulp)
  }
  __syncthreads();
  float* r = R + (long)row*512;
  for (int c=tid; c<512; c+=256){
    const float* w = pout_w + (long)c*128;
    float s = 0.f;
    #pragma unroll 4
    for (int d=0; d<128; d++) s += st_l[d]*w[d];
    r[c] = r[c] - (s + pout_b[c]);
  }
}

// zq32[b][c][t] = (float)z - R_final[row][c]   (z_q = z - residual, fp32)
__global__ void make_zq(const double* __restrict__ z, const float* __restrict__ R,
                        float* __restrict__ zq){
  long i = (long)blockIdx.x*256 + threadIdx.x;     // ROWS*512
  if (i >= (long)ROWS*512) return;
  int row = (int)(i >> 9); int c = (int)(i & 511);
  int b = row / T_RVQ, t = row - b*T_RVQ;
  long zi = ((long)b*512 + c)*T_RVQ + t;
  zq[zi] = (float)z[zi] - R[i];
}

__global__ void loss_final(const double* __restrict__ loss_acc, float* __restrict__ out){
  out[0] = (float)(loss_acc[0] * (1.25 / 2039808.0));   // 1.25/(64*249*128)
}

// ---------------------------------------------------------------------------
extern "C" void kernel_launch(void* const* d_in, const int* in_sizes, int n_in,
                              void* d_out, int out_size, void* d_ws, size_t ws_size,
                              hipStream_t stream)
{
  (void)in_sizes; (void)n_in; (void)out_size; (void)ws_size;
  const float* audio  = (const float*)d_in[0];
  const float* ew0=(const float*)d_in[1],  *eb0=(const float*)d_in[2],  *ea0=(const float*)d_in[3];
  const float* ew1=(const float*)d_in[4],  *eb1=(const float*)d_in[5],  *ea1=(const float*)d_in[6];
  const float* ew2=(const float*)d_in[7],  *eb2=(const float*)d_in[8],  *ea2=(const float*)d_in[9];
  const float* ew3=(const float*)d_in[10], *eb3=(const float*)d_in[11], *ea3=(const float*)d_in[12];
  const float* dw0=(const float*)d_in[13], *db0=(const float*)d_in[14], *da0=(const float*)d_in[15];
  const float* dw1=(const float*)d_in[16], *db1=(const float*)d_in[17], *da1=(const float*)d_in[18];
  const float* dw2=(const float*)d_in[19], *db2=(const float*)d_in[20], *da2=(const float*)d_in[21];
  const float* dw3=(const float*)d_in[22], *db3=(const float*)d_in[23];
  const float* pin_w =(const float*)d_in[24], *pin_b =(const float*)d_in[25];
  const float* pout_w=(const float*)d_in[26], *pout_b=(const float*)d_in[27];
  const float* cbs   =(const float*)d_in[28];

  float* out_audio = (float*)d_out;                 // 64*119688 = 7660032
  float* out_codes = out_audio + 7660032;           // 64*8*249  = 127488
  float* out_loss  = out_audio + 7787520;           // 1

  // ---- workspace layout (peak ~230 MB, lifetime-aliased) ----
  char* base = (char*)d_ws;
  // encoder phase (two batch halves):
  double* z64    = (double*)(base);                 // [64][512][249] f64 (65,273,856)
  double* e1half = (double*)(base +  65273856);     // [32][128][2999] f64 (98,271,232)
  double* e2half = (double*)(base + 163545088);     // [32][256][749]  f64 ends 212,631,552
  // fp32 RVQ phase (e1half/e2half dead; z64 LIVE until make_zq):
  float*  R      = (float*) (base +  65273856);     // [15936][512] f32 (32,636,928) ends 97,910,784
  float*  zp_f   = (float*) (base +  97910784);     // [15936][128] f32 (8,159,616) ends 106,070,400
  float*  zq32   = (float*) (base + 106070400);     // [64][512][249] f32 (32,636,928) ends 138,707,328
  // decoder phase:
  float*  d0out  = (float*) (base);                 // [64][256][748] (49,020,928) (z64/R dead)
  float*  d1out  = (float*) (base + 122560512);     // [64][128][2992] ends 220,602,368 (zq32 dead after D0)
  __half* d2h    = (__half*)(base);                 // [64][64][14961] fp16 (122,560,512)
  char* p = base + 220602368;
  auto alloc = [&](size_t bytes)->char*{
    char* r = p; p += (bytes + 255) & ~(size_t)255; return r;
  };
  float* wpE1 = (float*)alloc((size_t)128*64*10*4);
  float* wpE2 = (float*)alloc((size_t)256*128*8*4);
  float* wpE3 = (float*)alloc((size_t)512*256*6*4);
  float* wpD0 = (float*)alloc((size_t)512*256*6*4);
  float* wpD1 = (float*)alloc((size_t)256*128*8*4);
  float* wpD2 = (float*)alloc((size_t)128*64*10*4);
  float* cn2f = (float*)alloc((size_t)NB*NCODE*4);
  int* codesI = (int*)  alloc((size_t)ROWS*NB*4);
  double* lossA=(double*)alloc(256);

  // ---- packing / precompute ----
  pack_w_conv <<<cdiv(128*64*10,256),256,0,stream>>>(ew1, wpE1, 128, 64, 10);
  pack_w_conv <<<cdiv(256*128*8,256),256,0,stream>>>(ew2, wpE2, 256, 128, 8);
  pack_w_conv <<<cdiv(512*256*6,256),256,0,stream>>>(ew3, wpE3, 512, 256, 6);
  pack_w_convT<<<cdiv(512*256*6,256),256,0,stream>>>(dw0, wpD0, 512, 256, 6);
  pack_w_convT<<<cdiv(256*128*8,256),256,0,stream>>>(dw1, wpD1, 256, 128, 8);
  pack_w_convT<<<cdiv(128*64*10,256),256,0,stream>>>(dw2, wpD2, 128, 64, 10);
  prep_cn2f  <<<cdiv(NB*NCODE,256),256,0,stream>>>(cbs, cn2f);
  zero_loss  <<<1,1,0,stream>>>(lossA);

  // ---- encoder (E0 fused into E1; fp64; two batch halves) ----
  for (int h=0; h<2; h++){
    long b0 = 32L*h;
    conv_e0e1<<<dim3(cdiv(2999,64),2,32),256,0,stream>>>(
        audio + b0*120000, ew0, eb0, ea0, wpE1, eb1, ea1, e1half);
    conv_enc<128,256,8,4,2,8> <<<dim3(cdiv(749,64),4,32),256,0,stream>>>(
        e1half, wpE2, eb2, ea2, e2half, 2999, 749);
    conv_enc<256,512,6,3,1,8> <<<dim3(cdiv(249,64),8,32),256,0,stream>>>(
        e2half, wpE3, eb3, ea3, z64 + b0*512*249, 749, 249);
  }

  // ---- fp32 RVQ (reference-structured; update ALL 8 books) ----
  nv_transpose_f<<<cdiv(ROWS*512,256),256,0,stream>>>(z64, R);
  for (int bk=0; bk<NB; bk++){
    nv_proj_f<<<ROWS,128,0,stream>>>(R, pin_w, pin_b, zp_f);
    nv_dist_f<<<ROWS/32,256,0,stream>>>(zp_f, cbs + (long)bk*NCODE*128,
                                        cn2f + bk*NCODE, out_codes, codesI, lossA, bk);
    nv_update_f<<<ROWS,256,0,stream>>>(R, cbs + (long)bk*NCODE*128, zp_f,
                                       pout_w, pout_b, codesI, bk);
  }
  make_zq<<<cdiv(ROWS*512,256),256,0,stream>>>(z64, R, zq32);

  // ---- decoder ----
  convT_dec<512,256,6,3,1,16,float>  <<<dim3(cdiv(250,64)*3, 4,64),256,0,stream>>>(zq32, wpD0, db0, da0, d0out, 249, 748);
  convT_dec<256,128,8,4,2,16,float>  <<<dim3(cdiv(749,64)*4, 2,64),256,0,stream>>>(d0out, wpD1, db1, da1, d1out, 748, 2992);
  convT_dec<128,64,10,5,2,16,__half> <<<dim3(cdiv(2993,64)*5,1,64),256,0,stream>>>(d1out, wpD2, db2, da2, d2h, 2992, 14961);
  convT_last<<<dim3(cdiv(14962,1024),1,64),256,0,stream>>>(d2h, dw3, db3, out_audio);

  loss_final<<<1,1,0,stream>>>(lossA, out_loss);
}

// Round 7
// 8979.893 us; speedup vs baseline: 2.6930x; 2.6930x over previous
//
#include <hip/hip_runtime.h>
#include <hip/hip_fp16.h>
#include <math.h>

// ---------------------------------------------------------------------------
// SonataCodec forward. Round 7: performance pass on the round-6 green build.
//  - Decoder: phase-major intermediate layouts (coalesced writes, was x5
//    write amplification on D2: WRITE_SIZE 613MB for a 122MB output) +
//    float4 LDS reads (was 16 scalar b32 per 32 FMA).
//  - RVQ: tiled proj/dist/update with LDS-staged weights/codebook, float4
//    reads, SAME bit-exact fp32 per-output accumulation order as round 6.
//  - Encoder: unchanged fp64 (correctness-critical for codes; optimize next).
// ---------------------------------------------------------------------------

#define T_RVQ 249
#define ROWS  (64*249)     // 15936
#define NB    8
#define NCODE 1024

static inline int cdiv(int a, int b){ return (a+b-1)/b; }

// ---------------- pack kernels ----------------
__global__ void pack_w_conv(const float* __restrict__ w, float* __restrict__ wp,
                            int COUT, int CIN, int K){
  int i = blockIdx.x*256 + threadIdx.x;
  int tot = COUT*CIN*K;
  if (i >= tot) return;
  int co = i / (CIN*K); int r = i - co*(CIN*K);
  wp[(long)r*COUT + co] = w[i];
}
__global__ void pack_w_convT(const float* __restrict__ w, float* __restrict__ wp,
                             int CIN, int COUT, int K){
  int i = blockIdx.x*256 + threadIdx.x;
  int tot = CIN*COUT*K;
  if (i >= tot) return;
  int ci = i / (COUT*K); int r = i - ci*(COUT*K);
  int co = r / K; int j = r - co*K;
  wp[(long)(ci*K + j)*COUT + co] = w[i];
}
__global__ void prep_cn2f(const float* __restrict__ cbs, float* __restrict__ cn2){
  int i = blockIdx.x*256 + threadIdx.x;  // 8192 codes
  if (i >= NB*NCODE) return;
  const float* c = cbs + (long)i*128;
  float s = 0.f;
  for (int d=0; d<128; d++) s += c[d]*c[d];
  cn2[i] = s;
}
__global__ void zero_loss(double* p){ p[0] = 0.0; }

// ---------------- fused E0+E1 (all fp64, fp64 out) -------------------------
__global__ __launch_bounds__(256) void conv_e0e1(
    const float* __restrict__ audio,   // [32][120000] (offset view)
    const float* __restrict__ w0,      // [64][16]
    const float* __restrict__ b0v, const float* __restrict__ a0v,
    const float* __restrict__ wp1,     // packed [64*10][128]
    const float* __restrict__ b1v, const float* __restrict__ a1v,
    double* __restrict__ out)          // [32][128][2999] fp64
{
  constexpr int WIDTH = 63*5 + 10;        // 325 E0 positions
  constexpr int AW    = (WIDTH-1)*8 + 16; // 2608 audio samples
  __shared__ double aud_s[AW];
  __shared__ double w0_s[64][16];
  __shared__ double b0_s[64], a0_s[64], i0_s[64];
  __shared__ double xs[4][WIDTH];
  __shared__ double ws[40][64];
  const int tid  = threadIdx.x;
  const int lo_t = tid & 15;
  const int co_t = tid >> 4;
  const int b    = blockIdx.z;
  const int co0  = blockIdx.y*64;
  const int lo0  = blockIdx.x*64;
  const int g0   = lo0*5 - 2;
  const long aud0 = (long)g0*8 - 4;
  for (int idx=tid; idx<AW; idx+=256){
    long s = aud0 + idx;
    aud_s[idx] = (s>=0 && s<120000) ? (double)audio[(long)b*120000 + s] : 0.0;
  }
  for (int idx=tid; idx<1024; idx+=256)
    w0_s[idx>>4][idx&15] = (double)w0[idx];
  if (tid < 64){
    b0_s[tid] = (double)b0v[tid];
    double a = (double)a0v[tid];
    a0_s[tid] = a; i0_s[tid] = 1.0/a;
  }
  double acc[4][4];
  #pragma unroll
  for (int c=0;c<4;c++){ acc[c][0]=0; acc[c][1]=0; acc[c][2]=0; acc[c][3]=0; }
  for (int ci0=0; ci0<64; ci0+=4){
    __syncthreads();
    for (int idx=tid; idx<4*WIDTH; idx+=256){
      int cich = idx / WIDTH, p = idx - cich*WIDTH;
      int ci = ci0 + cich;
      double v = b0_s[ci];
      #pragma unroll
      for (int j=0;j<16;j++) v += w0_s[ci][j]*aud_s[p*8 + j];
      double sn = sin(a0_s[ci]*v);
      double e0 = v + i0_s[ci]*sn*sn;
      int g = g0 + p;
      xs[cich][p] = (g>=0 && g<15000) ? e0 : 0.0;
    }
    for (int idx=tid; idx<40*64; idx+=256){
      int col = idx & 63, r = idx >> 6;
      ws[r][col] = (double)wp1[(long)(ci0*10 + r)*128 + co0 + col];
    }
    __syncthreads();
    for (int cich=0; cich<4; cich++){
      #pragma unroll
      for (int j=0;j<10;j++){
        double wv0 = ws[cich*10+j][co_t     ];
        double wv1 = ws[cich*10+j][co_t + 16];
        double wv2 = ws[cich*10+j][co_t + 32];
        double wv3 = ws[cich*10+j][co_t + 48];
        #pragma unroll
        for (int m=0;m<4;m++){
          double xv = xs[cich][(lo_t + 16*m)*5 + j];
          acc[0][m] += wv0*xv; acc[1][m] += wv1*xv;
          acc[2][m] += wv2*xv; acc[3][m] += wv3*xv;
        }
      }
    }
  }
  #pragma unroll
  for (int c=0;c<4;c++){
    int co = co0 + co_t + 16*c;
    double bv  = (double)b1v[co];
    double a   = (double)a1v[co];
    double inv = 1.0/a;
    #pragma unroll
    for (int m=0;m<4;m++){
      int lo = lo0 + lo_t + 16*m;
      if (lo < 2999){
        double v = acc[c][m] + bv;
        double sn = sin(a*v);
        v = v + inv*sn*sn;
        out[((long)b*128 + co)*2999 + lo] = v;
      }
    }
  }
}

// ---------------- encoder conv E2/E3 (fp64 in, fp64 out) -------------------
template<int CIN,int COUT,int K,int S,int PAD,int CICH>
__global__ __launch_bounds__(256) void conv_enc(
    const double* __restrict__ x, const float* __restrict__ wp,
    const float* __restrict__ bias, const float* __restrict__ alpha,
    double* __restrict__ out, int Lin, int Lout)
{
  constexpr int WIDTH = 63*S + K;
  __shared__ double xs[CICH][WIDTH];
  __shared__ double ws[CICH*K][64];
  const int tid  = threadIdx.x;
  const int lo_t = tid & 15;
  const int co_t = tid >> 4;
  const int b    = blockIdx.z;
  const int co0  = blockIdx.y*64;
  const int lo0  = blockIdx.x*64;
  const int x0   = lo0*S - PAD;
  const long xb  = (long)b*CIN*Lin;
  double acc[4][4];
  #pragma unroll
  for (int c=0;c<4;c++){ acc[c][0]=0; acc[c][1]=0; acc[c][2]=0; acc[c][3]=0; }
  for (int ci0=0; ci0<CIN; ci0+=CICH){
    __syncthreads();
    for (int idx=tid; idx<CICH*WIDTH; idx+=256){
      int ci = idx / WIDTH, p = idx - ci*WIDTH;
      int g = x0 + p;
      xs[ci][p] = (g>=0 && g<Lin) ? x[xb + (long)(ci0+ci)*Lin + g] : 0.0;
    }
    for (int idx=tid; idx<CICH*K*64; idx+=256){
      int col = idx & 63, r = idx >> 6;
      ws[r][col] = (double)wp[(long)(ci0*K + r)*COUT + co0 + col];
    }
    __syncthreads();
    for (int ci=0; ci<CICH; ci++){
      #pragma unroll
      for (int j=0;j<K;j++){
        double w0 = ws[ci*K+j][co_t     ];
        double w1 = ws[ci*K+j][co_t + 16];
        double w2 = ws[ci*K+j][co_t + 32];
        double w3 = ws[ci*K+j][co_t + 48];
        #pragma unroll
        for (int m=0;m<4;m++){
          double xv = xs[ci][(lo_t + 16*m)*S + j];
          acc[0][m] += w0*xv; acc[1][m] += w1*xv;
          acc[2][m] += w2*xv; acc[3][m] += w3*xv;
        }
      }
    }
  }
  #pragma unroll
  for (int c=0;c<4;c++){
    int co = co0 + co_t + 16*c;
    double bv  = (double)bias[co];
    double a   = (double)alpha[co];
    double inv = 1.0/a;
    #pragma unroll
    for (int m=0;m<4;m++){
      int lo = lo0 + lo_t + 16*m;
      if (lo < Lout){
        double v = acc[c][m] + bv;
        double sn = sin(a*v);
        v = v + inv*sn*sn;
        out[((long)b*COUT + co)*Lout + lo] = v;
      }
    }
  }
}

// ---------------- decoder transposed conv, phase-major I/O -----------------
// Output layout: out[((b*COUT+co)*S + r)*T1OUT + t1], lo = t1*S + r - PAD.
// Input: IMODE=0 plain [b][ci][t]; IMODE=1 phase-major from previous layer
// (u = t + IPAD; rr = u % IS; tt = u / IS).
template<int CIN,int COUT,int K,int S,int PAD,int CICH,
         int IMODE,int IS,int IT1,int IPAD,int T1OUT,int LOUT,typename OUTT>
__global__ __launch_bounds__(256) void convT_pm(
    const float* __restrict__ x, const float* __restrict__ wp,
    const float* __restrict__ bias, const float* __restrict__ alpha,
    OUTT* __restrict__ out, int Lin)
{
  __shared__ float xs[CICH][68];
  __shared__ float ws[CICH][2][64];
  const int tid  = threadIdx.x;
  const int lo_t = tid & 15;      // t1 = t10 + lo_t*4 + j  (contiguous 4)
  const int co_t = tid >> 4;      // co = co0 + co_t*4 + c  (contiguous 4)
  const int bx   = blockIdx.x;
  const int r    = bx % S;
  const int t10  = (bx / S) * 64;
  const int b    = blockIdx.z;
  const int co0  = blockIdx.y*64;
  float acc[4][4];
  #pragma unroll
  for (int c=0;c<4;c++){ acc[c][0]=0; acc[c][1]=0; acc[c][2]=0; acc[c][3]=0; }
  for (int ci0=0; ci0<CIN; ci0+=CICH){
    __syncthreads();
    for (int idx=tid; idx<CICH*65; idx+=256){
      int ci = idx / 65, p = idx - ci*65;
      int t = t10 - 1 + p;
      float v = 0.f;
      if (t >= 0 && t < Lin){
        long bci = (long)b*CIN + ci0 + ci;
        if (IMODE == 0) v = x[bci*Lin + t];
        else { int u = t + IPAD; int rr = u % IS; int tt = u / IS;
               v = x[(bci*IS + rr)*IT1 + tt]; }
      }
      xs[ci][p] = v;
    }
    for (int idx=tid; idx<CICH*2*64; idx+=256){
      int col = idx & 63, q = idx >> 6;
      int ci = q >> 1, tap = q & 1;
      ws[ci][tap][col] = wp[(long)((ci0+ci)*K + r + tap*S)*COUT + co0 + col];
    }
    __syncthreads();
    for (int ci=0; ci<CICH; ci++){
      float4 wa = *(const float4*)&ws[ci][0][co_t*4];
      float4 wb = *(const float4*)&ws[ci][1][co_t*4];
      float4 xv = *(const float4*)&xs[ci][lo_t*4];
      float  xe = xs[ci][lo_t*4 + 4];
      float xp[5] = {xv.x, xv.y, xv.z, xv.w, xe};
      #pragma unroll
      for (int j=0;j<4;j++){
        float xa = xp[j+1];   // x[t1]
        float xb2 = xp[j];    // x[t1-1]
        acc[0][j] += wa.x*xa + wb.x*xb2;
        acc[1][j] += wa.y*xa + wb.y*xb2;
        acc[2][j] += wa.z*xa + wb.z*xb2;
        acc[3][j] += wa.w*xa + wb.w*xb2;
      }
    }
  }
  #pragma unroll
  for (int c=0;c<4;c++){
    int co = co0 + co_t*4 + c;
    float bv  = bias[co];
    float a   = alpha[co];
    float inv = 1.f/a;
    long obase = ((long)((long)b*COUT + co)*S + r)*T1OUT;
    #pragma unroll
    for (int j=0;j<4;j++){
      int t1 = t10 + lo_t*4 + j;
      int lo = t1*S + r - PAD;
      if (t1 < T1OUT && lo >= 0 && lo < LOUT){
        float v = acc[c][j] + bv;
        float sn = __sinf(a*v);
        v = v + inv*sn*sn;
        out[obase + t1] = OUTT(v);
      }
    }
  }
}

// ---------------- final decoder layer (reads D2 phase-major fp16) ----------
__global__ __launch_bounds__(256) void convT_last(
    const __half* __restrict__ x,  // pm [64][64][5][2993] fp16
    const float* __restrict__ w,   // [64][1][16]
    const float* __restrict__ bias,
    float* __restrict__ out)       // [64][119688]
{
  constexpr int LIN = 14961, LOUT = 119688, CIN = 64;
  __shared__ __align__(16) float xs[8][1028];
  __shared__ float ws[8][16];
  const int tid = threadIdx.x;
  const int b   = blockIdx.z;
  const int t10 = blockIdx.x*1024;
  float acc[4][8];
  #pragma unroll
  for (int u=0;u<4;u++) for (int rr=0;rr<8;rr++) acc[u][rr]=0.f;
  for (int ci0=0; ci0<CIN; ci0+=8){
    __syncthreads();
    for (int idx=tid; idx<8*1025; idx+=256){
      int ci = idx / 1025, p = idx - ci*1025;
      int t = t10 - 1 + p;
      float v = 0.f;
      if (t >= 0 && t < LIN){
        int u = t + 2; int rr = u % 5; int tt = u / 5;
        v = __half2float(x[((long)((long)b*CIN + ci0+ci)*5 + rr)*2993 + tt]);
      }
      xs[ci][p] = v;
    }
    if (tid < 128){
      int ci = tid >> 4, j = tid & 15;
      ws[ci][j] = w[(ci0+ci)*16 + j];
    }
    __syncthreads();
    #pragma unroll 2
    for (int ci=0; ci<8; ci++){
      float4 xv = *(const float4*)&xs[ci][tid*4];
      float  xe = xs[ci][tid*4 + 4];
      float xb_[5] = {xv.x, xv.y, xv.z, xv.w, xe};
      #pragma unroll
      for (int u=0;u<4;u++){
        float xprev = xb_[u];
        float xcur  = xb_[u+1];
        #pragma unroll
        for (int rr=0; rr<8; rr++)
          acc[u][rr] += ws[ci][rr]*xcur + ws[ci][rr+8]*xprev;
      }
    }
  }
  float bv = bias[0];
  #pragma unroll
  for (int u=0;u<4;u++){
    int t1 = t10 + tid*4 + u;
    #pragma unroll
    for (int rr=0;rr<8;rr++){
      int lo = t1*8 + rr - 4;
      if (lo >= 0 && lo < LOUT)
        out[(long)b*LOUT + lo] = tanhf(acc[u][rr] + bv);
    }
  }
}

// ======================= fp32 RVQ (tiled, bit-exact vs round 6) ============
__global__ void nv_transpose_f(const double* __restrict__ z, float* __restrict__ R){
  long i = (long)blockIdx.x*256 + threadIdx.x;     // ROWS*512
  if (i >= (long)ROWS*512) return;
  int row = (int)(i >> 9); int c = (int)(i & 511);
  int b = row / T_RVQ, t = row - b*T_RVQ;
  R[i] = (float)z[((long)b*512 + c)*T_RVQ + t];
}

// zp[row][d] = (sum_c ascending R*w) + pin_b[d]; 32 rows/block.
__global__ __launch_bounds__(256) void rvq_proj_t(
    const float* __restrict__ R, const float* __restrict__ pin_w,
    const float* __restrict__ pin_b, float* __restrict__ zp)
{
  __shared__ float Rs[64][36];
  __shared__ float Ps[64][132];
  const int tid = threadIdx.x;
  const int row0 = blockIdx.x*32;
  const int d_t = tid & 31;       // d = d_t*4 + j
  const int r_t = tid >> 5;       // row = r_t*4 + k
  float acc[4][4];
  #pragma unroll
  for (int k=0;k<4;k++){ acc[k][0]=0; acc[k][1]=0; acc[k][2]=0; acc[k][3]=0; }
  for (int c0=0; c0<512; c0+=64){
    __syncthreads();
    for (int idx=tid; idx<2048; idx+=256){
      int c = idx & 63, r = idx >> 6;
      Rs[c][r] = R[(long)(row0+r)*512 + c0 + c];
    }
    for (int idx=tid; idx<8192; idx+=256){
      int c = idx & 63, d = idx >> 6;
      Ps[c][d] = pin_w[(long)d*512 + c0 + c];
    }
    __syncthreads();
    for (int c=0; c<64; c++){
      float4 rv = *(const float4*)&Rs[c][r_t*4];
      float4 wv = *(const float4*)&Ps[c][d_t*4];
      acc[0][0] += rv.x*wv.x; acc[0][1] += rv.x*wv.y; acc[0][2] += rv.x*wv.z; acc[0][3] += rv.x*wv.w;
      acc[1][0] += rv.y*wv.x; acc[1][1] += rv.y*wv.y; acc[1][2] += rv.y*wv.z; acc[1][3] += rv.y*wv.w;
      acc[2][0] += rv.z*wv.x; acc[2][1] += rv.z*wv.y; acc[2][2] += rv.z*wv.z; acc[2][3] += rv.z*wv.w;
      acc[3][0] += rv.w*wv.x; acc[3][1] += rv.w*wv.y; acc[3][2] += rv.w*wv.z; acc[3][3] += rv.w*wv.w;
    }
  }
  #pragma unroll
  for (int k=0;k<4;k++){
    int row = row0 + r_t*4 + k;
    #pragma unroll
    for (int j=0;j<4;j++){
      int d = d_t*4 + j;
      zp[(long)row*128 + d] = acc[k][j] + pin_b[d];
    }
  }
}

// d2 = (zp2 - 2*dot) + cn2 (fp32 grid, ascending-d dot, first-min argmin).
__global__ __launch_bounds__(256) void rvq_dist_t(
    const float* __restrict__ zp, const float* __restrict__ cb,
    const float* __restrict__ cn2, float* __restrict__ codes_out,
    int* __restrict__ codes_int, double* __restrict__ loss_acc, int book)
{
  __shared__ float zp_l[32][129];
  __shared__ float zp2_l[32];
  __shared__ float cb_s[32][132];
  __shared__ float cn2_s[128];
  __shared__ float sv[32][33];
  __shared__ int   si[32][33];
  __shared__ double ls[32];
  const int tid = threadIdx.x;
  const int row0 = blockIdx.x*32;
  const int n_t = tid & 31;       // code = tile*128 + n_t*4 + j
  const int r_t = tid >> 5;       // row  = r_t + 8*k
  for (int idx=tid; idx<32*128; idx+=256){
    int r = idx >> 7, d = idx & 127;
    zp_l[r][d] = zp[(long)(row0+r)*128 + d];
  }
  __syncthreads();
  if (tid < 32){
    float s2 = 0.f;
    for (int d=0; d<128; d++) s2 += zp_l[tid][d]*zp_l[tid][d];
    zp2_l[tid] = s2;
  }
  float best[4]; int bi[4];
  #pragma unroll
  for (int k=0;k<4;k++){ best[k]=3.4e38f; bi[k]=0; }
  for (int tile=0; tile<8; tile++){
    __syncthreads();
    if (tid < 128) cn2_s[tid] = cn2[tile*128 + tid];
    float dot[4][4];
    #pragma unroll
    for (int k=0;k<4;k++){ dot[k][0]=0; dot[k][1]=0; dot[k][2]=0; dot[k][3]=0; }
    for (int dch=0; dch<4; dch++){
      __syncthreads();
      for (int idx=tid; idx<128*32; idx+=256){
        int dd = idx & 31, n = idx >> 5;
        cb_s[dd][n] = cb[(long)(tile*128 + n)*128 + dch*32 + dd];
      }
      __syncthreads();
      for (int dd=0; dd<32; dd++){
        float4 cv = *(const float4*)&cb_s[dd][n_t*4];
        float zr[4];
        #pragma unroll
        for (int k=0;k<4;k++) zr[k] = zp_l[r_t + 8*k][dch*32 + dd];
        #pragma unroll
        for (int k=0;k<4;k++){
          dot[k][0] += zr[k]*cv.x; dot[k][1] += zr[k]*cv.y;
          dot[k][2] += zr[k]*cv.z; dot[k][3] += zr[k]*cv.w;
        }
      }
    }
    #pragma unroll
    for (int k=0;k<4;k++){
      float z2 = zp2_l[r_t + 8*k];
      #pragma unroll
      for (int j=0;j<4;j++){
        int n = n_t*4 + j;
        float dist = (z2 - 2.0f*dot[k][j]) + cn2_s[n];
        int gn = tile*128 + n;
        if (dist < best[k]){ best[k]=dist; bi[k]=gn; }
      }
    }
  }
  __syncthreads();
  #pragma unroll
  for (int k=0;k<4;k++){
    sv[r_t + 8*k][n_t] = best[k];
    si[r_t + 8*k][n_t] = bi[k];
  }
  __syncthreads();
  if (tid < 32){
    float b2 = sv[tid][0]; int i2 = si[tid][0];
    for (int q=1; q<32; q++){
      float v = sv[tid][q]; int ii = si[tid][q];
      if (v < b2 || (v == b2 && ii < i2)){ b2=v; i2=ii; }
    }
    int row = row0 + tid;
    int bb = row / T_RVQ, t = row - bb*T_RVQ;
    codes_out[bb*(NB*T_RVQ) + book*T_RVQ + t] = (float)i2;
    codes_int[(long)row*NB + book] = i2;
    ls[tid] = (double)b2;
  }
  __syncthreads();
  if (tid == 0){
    double s = 0.0;
    for (int rr=0;rr<32;rr++) s += ls[rr];
    atomicAdd(loss_acc, s);
  }
}

// R[row][c] -= (sum_d ascending st*w) + pout_b[c]; st = zp + (zq - zp).
__global__ __launch_bounds__(256) void rvq_update_t(
    float* __restrict__ R, const float* __restrict__ cb,
    const float* __restrict__ zp, const float* __restrict__ pout_w,
    const float* __restrict__ pout_b, const int* __restrict__ codes_int,
    int book)
{
  __shared__ float st_l[32][128];
  __shared__ float po_s[64][132];
  __shared__ int code_l[32];
  const int tid = threadIdx.x;
  const int row0 = blockIdx.x*32;
  if (tid < 32) code_l[tid] = codes_int[(long)(row0+tid)*NB + book];
  __syncthreads();
  for (int idx=tid; idx<32*128; idx+=256){
    int r = idx >> 7, d = idx & 127;
    float zpv = zp[(long)(row0+r)*128 + d];
    float zqv = cb[(long)code_l[r]*128 + d];
    st_l[r][d] = zpv + (zqv - zpv);
  }
  const int r_t = tid >> 3;       // 0..31 row
  const int cl  = tid & 7;
  for (int c0=0; c0<512; c0+=64){
    __syncthreads();
    for (int idx=tid; idx<64*128; idx+=256){
      int d = idx & 127, c = idx >> 7;
      po_s[c][d] = pout_w[(long)(c0+c)*128 + d];
    }
    __syncthreads();
    float s[8];
    #pragma unroll
    for (int ii=0;ii<8;ii++) s[ii] = 0.f;
    for (int d4=0; d4<128; d4+=4){
      float4 sv4 = *(const float4*)&st_l[r_t][d4];
      #pragma unroll
      for (int ii=0; ii<8; ii++){
        float4 wv4 = *(const float4*)&po_s[cl + 8*ii][d4];
        s[ii] += sv4.x*wv4.x; s[ii] += sv4.y*wv4.y;
        s[ii] += sv4.z*wv4.z; s[ii] += sv4.w*wv4.w;
      }
    }
    #pragma unroll
    for (int ii=0; ii<8; ii++){
      int c = c0 + cl + 8*ii;
      long gi = (long)(row0 + r_t)*512 + c;
      R[gi] = R[gi] - (s[ii] + pout_b[c]);
    }
  }
}

// zq32[b][c][t] = (float)z - R_final[row][c]
__global__ void make_zq(const double* __restrict__ z, const float* __restrict__ R,
                        float* __restrict__ zq){
  long i = (long)blockIdx.x*256 + threadIdx.x;     // ROWS*512
  if (i >= (long)ROWS*512) return;
  int row = (int)(i >> 9); int c = (int)(i & 511);
  int b = row / T_RVQ, t = row - b*T_RVQ;
  long zi = ((long)b*512 + c)*T_RVQ + t;
  zq[zi] = (float)z[zi] - R[i];
}

__global__ void loss_final(const double* __restrict__ loss_acc, float* __restrict__ out){
  out[0] = (float)(loss_acc[0] * (1.25 / 2039808.0));   // 1.25/(64*249*128)
}

// ---------------------------------------------------------------------------
extern "C" void kernel_launch(void* const* d_in, const int* in_sizes, int n_in,
                              void* d_out, int out_size, void* d_ws, size_t ws_size,
                              hipStream_t stream)
{
  (void)in_sizes; (void)n_in; (void)out_size; (void)ws_size;
  const float* audio  = (const float*)d_in[0];
  const float* ew0=(const float*)d_in[1],  *eb0=(const float*)d_in[2],  *ea0=(const float*)d_in[3];
  const float* ew1=(const float*)d_in[4],  *eb1=(const float*)d_in[5],  *ea1=(const float*)d_in[6];
  const float* ew2=(const float*)d_in[7],  *eb2=(const float*)d_in[8],  *ea2=(const float*)d_in[9];
  const float* ew3=(const float*)d_in[10], *eb3=(const float*)d_in[11], *ea3=(const float*)d_in[12];
  const float* dw0=(const float*)d_in[13], *db0=(const float*)d_in[14], *da0=(const float*)d_in[15];
  const float* dw1=(const float*)d_in[16], *db1=(const float*)d_in[17], *da1=(const float*)d_in[18];
  const float* dw2=(const float*)d_in[19], *db2=(const float*)d_in[20], *da2=(const float*)d_in[21];
  const float* dw3=(const float*)d_in[22], *db3=(const float*)d_in[23];
  const float* pin_w =(const float*)d_in[24], *pin_b =(const float*)d_in[25];
  const float* pout_w=(const float*)d_in[26], *pout_b=(const float*)d_in[27];
  const float* cbs   =(const float*)d_in[28];

  float* out_audio = (float*)d_out;                 // 64*119688 = 7660032
  float* out_codes = out_audio + 7660032;           // 64*8*249  = 127488
  float* out_loss  = out_audio + 7787520;           // 1

  // ---- workspace layout (peak ~230.5 MB, lifetime-aliased) ----
  char* base = (char*)d_ws;
  // encoder phase (two batch halves):
  double* z64    = (double*)(base);                 // [64][512][249] f64 (65,273,856)
  double* e1half = (double*)(base +  65273856);     // [32][128][2999] f64
  double* e2half = (double*)(base + 163545088);     // [32][256][749]  f64 ends 212,631,552
  // fp32 RVQ phase (z64 LIVE until make_zq):
  float*  R      = (float*) (base +  65273856);     // [15936][512] ends 97,910,784
  float*  zp_f   = (float*) (base +  97910784);     // [15936][128] ends 106,070,400
  float*  zq32   = (float*) (base + 106070400);     // [64][512][249] ends 138,707,328
  // decoder phase (phase-major intermediates):
  float*  d0pm   = (float*) (base);                 // [64][256][3][250] 49,152,000 (z64 dead)
  float*  d1pm   = (float*) (base + 122683392);     // [64][128][4][749] ends 220,856,320
  __half* d2pm   = (__half*)(base);                 // [64][64][5][2993] 122,593,280 (d0pm/zq32 dead)
  char* p = base + 220856320;
  auto alloc = [&](size_t bytes)->char*{
    char* r = p; p += (bytes + 255) & ~(size_t)255; return r;
  };
  float* wpE1 = (float*)alloc((size_t)128*64*10*4);
  float* wpE2 = (float*)alloc((size_t)256*128*8*4);
  float* wpE3 = (float*)alloc((size_t)512*256*6*4);
  float* wpD0 = (float*)alloc((size_t)512*256*6*4);
  float* wpD1 = (float*)alloc((size_t)256*128*8*4);
  float* wpD2 = (float*)alloc((size_t)128*64*10*4);
  float* cn2f = (float*)alloc((size_t)NB*NCODE*4);
  int* codesI = (int*)  alloc((size_t)ROWS*NB*4);
  double* lossA=(double*)alloc(256);

  // ---- packing / precompute ----
  pack_w_conv <<<cdiv(128*64*10,256),256,0,stream>>>(ew1, wpE1, 128, 64, 10);
  pack_w_conv <<<cdiv(256*128*8,256),256,0,stream>>>(ew2, wpE2, 256, 128, 8);
  pack_w_conv <<<cdiv(512*256*6,256),256,0,stream>>>(ew3, wpE3, 512, 256, 6);
  pack_w_convT<<<cdiv(512*256*6,256),256,0,stream>>>(dw0, wpD0, 512, 256, 6);
  pack_w_convT<<<cdiv(256*128*8,256),256,0,stream>>>(dw1, wpD1, 256, 128, 8);
  pack_w_convT<<<cdiv(128*64*10,256),256,0,stream>>>(dw2, wpD2, 128, 64, 10);
  prep_cn2f  <<<cdiv(NB*NCODE,256),256,0,stream>>>(cbs, cn2f);
  zero_loss  <<<1,1,0,stream>>>(lossA);

  // ---- encoder (E0 fused into E1; fp64; two batch halves) ----
  for (int h=0; h<2; h++){
    long b0 = 32L*h;
    conv_e0e1<<<dim3(cdiv(2999,64),2,32),256,0,stream>>>(
        audio + b0*120000, ew0, eb0, ea0, wpE1, eb1, ea1, e1half);
    conv_enc<128,256,8,4,2,8> <<<dim3(cdiv(749,64),4,32),256,0,stream>>>(
        e1half, wpE2, eb2, ea2, e2half, 2999, 749);
    conv_enc<256,512,6,3,1,8> <<<dim3(cdiv(249,64),8,32),256,0,stream>>>(
        e2half, wpE3, eb3, ea3, z64 + b0*512*249, 749, 249);
  }

  // ---- fp32 RVQ (tiled; bit-exact arithmetic order vs round 6) ----
  nv_transpose_f<<<cdiv(ROWS*512,256),256,0,stream>>>(z64, R);
  for (int bk=0; bk<NB; bk++){
    rvq_proj_t<<<ROWS/32,256,0,stream>>>(R, pin_w, pin_b, zp_f);
    rvq_dist_t<<<ROWS/32,256,0,stream>>>(zp_f, cbs + (long)bk*NCODE*128,
                                         cn2f + bk*NCODE, out_codes, codesI, lossA, bk);
    rvq_update_t<<<ROWS/32,256,0,stream>>>(R, cbs + (long)bk*NCODE*128, zp_f,
                                           pout_w, pout_b, codesI, bk);
  }
  make_zq<<<cdiv(ROWS*512,256),256,0,stream>>>(z64, R, zq32);

  // ---- decoder (phase-major) ----
  convT_pm<512,256,6,3,1,16, 0,1,1,0, 250, 748, float>
      <<<dim3(cdiv(250,64)*3, 4, 64),256,0,stream>>>(zq32, wpD0, db0, da0, d0pm, 249);
  convT_pm<256,128,8,4,2,16, 1,3,250,1, 749, 2992, float>
      <<<dim3(cdiv(749,64)*4, 2, 64),256,0,stream>>>(d0pm, wpD1, db1, da1, d1pm, 748);
  convT_pm<128,64,10,5,2,16, 1,4,749,2, 2993, 14961, __half>
      <<<dim3(cdiv(2993,64)*5, 1, 64),256,0,stream>>>(d1pm, wpD2, db2, da2, d2pm, 2992);
  convT_last<<<dim3(cdiv(14962,1024),1,64),256,0,stream>>>(d2pm, dw3, db3, out_audio);

  loss_final<<<1,1,0,stream>>>(lossA, out_loss);
}

// Round 8
// 8329.327 us; speedup vs baseline: 2.9033x; 1.0781x over previous
//
#include <hip/hip_runtime.h>
#include <hip/hip_fp16.h>
#include <math.h>

// ---------------------------------------------------------------------------
// SonataCodec forward. Round 8: decoder convT restructured r-major-in-block.
// r7 profile: D2 convT FETCH 390MB = 4x input (each phase-block restaged the
// same input window) and low FMA density. Now one block computes ALL S phases
// for a 64co x 64t1 tile: xs staged once per ci-chunk, weights per (r,chunk)
// from L2. acc[S][16] per thread (static indexing, full r unroll).
// Encoder (fp64) and RVQ (fp32-grid, bit-exact) untouched -> codes identical.
// ---------------------------------------------------------------------------

#define T_RVQ 249
#define ROWS  (64*249)     // 15936
#define NB    8
#define NCODE 1024

static inline int cdiv(int a, int b){ return (a+b-1)/b; }

// ---------------- pack kernels ----------------
__global__ void pack_w_conv(const float* __restrict__ w, float* __restrict__ wp,
                            int COUT, int CIN, int K){
  int i = blockIdx.x*256 + threadIdx.x;
  int tot = COUT*CIN*K;
  if (i >= tot) return;
  int co = i / (CIN*K); int r = i - co*(CIN*K);
  wp[(long)r*COUT + co] = w[i];
}
__global__ void pack_w_convT(const float* __restrict__ w, float* __restrict__ wp,
                             int CIN, int COUT, int K){
  int i = blockIdx.x*256 + threadIdx.x;
  int tot = CIN*COUT*K;
  if (i >= tot) return;
  int ci = i / (COUT*K); int r = i - ci*(COUT*K);
  int co = r / K; int j = r - co*K;
  wp[(long)(ci*K + j)*COUT + co] = w[i];
}
__global__ void prep_cn2f(const float* __restrict__ cbs, float* __restrict__ cn2){
  int i = blockIdx.x*256 + threadIdx.x;  // 8192 codes
  if (i >= NB*NCODE) return;
  const float* c = cbs + (long)i*128;
  float s = 0.f;
  for (int d=0; d<128; d++) s += c[d]*c[d];
  cn2[i] = s;
}
__global__ void zero_loss(double* p){ p[0] = 0.0; }

// ---------------- fused E0+E1 (all fp64, fp64 out) -------------------------
__global__ __launch_bounds__(256) void conv_e0e1(
    const float* __restrict__ audio,   // [32][120000] (offset view)
    const float* __restrict__ w0,      // [64][16]
    const float* __restrict__ b0v, const float* __restrict__ a0v,
    const float* __restrict__ wp1,     // packed [64*10][128]
    const float* __restrict__ b1v, const float* __restrict__ a1v,
    double* __restrict__ out)          // [32][128][2999] fp64
{
  constexpr int WIDTH = 63*5 + 10;        // 325 E0 positions
  constexpr int AW    = (WIDTH-1)*8 + 16; // 2608 audio samples
  __shared__ double aud_s[AW];
  __shared__ double w0_s[64][16];
  __shared__ double b0_s[64], a0_s[64], i0_s[64];
  __shared__ double xs[4][WIDTH];
  __shared__ double ws[40][64];
  const int tid  = threadIdx.x;
  const int lo_t = tid & 15;
  const int co_t = tid >> 4;
  const int b    = blockIdx.z;
  const int co0  = blockIdx.y*64;
  const int lo0  = blockIdx.x*64;
  const int g0   = lo0*5 - 2;
  const long aud0 = (long)g0*8 - 4;
  for (int idx=tid; idx<AW; idx+=256){
    long s = aud0 + idx;
    aud_s[idx] = (s>=0 && s<120000) ? (double)audio[(long)b*120000 + s] : 0.0;
  }
  for (int idx=tid; idx<1024; idx+=256)
    w0_s[idx>>4][idx&15] = (double)w0[idx];
  if (tid < 64){
    b0_s[tid] = (double)b0v[tid];
    double a = (double)a0v[tid];
    a0_s[tid] = a; i0_s[tid] = 1.0/a;
  }
  double acc[4][4];
  #pragma unroll
  for (int c=0;c<4;c++){ acc[c][0]=0; acc[c][1]=0; acc[c][2]=0; acc[c][3]=0; }
  for (int ci0=0; ci0<64; ci0+=4){
    __syncthreads();
    for (int idx=tid; idx<4*WIDTH; idx+=256){
      int cich = idx / WIDTH, p = idx - cich*WIDTH;
      int ci = ci0 + cich;
      double v = b0_s[ci];
      #pragma unroll
      for (int j=0;j<16;j++) v += w0_s[ci][j]*aud_s[p*8 + j];
      double sn = sin(a0_s[ci]*v);
      double e0 = v + i0_s[ci]*sn*sn;
      int g = g0 + p;
      xs[cich][p] = (g>=0 && g<15000) ? e0 : 0.0;
    }
    for (int idx=tid; idx<40*64; idx+=256){
      int col = idx & 63, r = idx >> 6;
      ws[r][col] = (double)wp1[(long)(ci0*10 + r)*128 + co0 + col];
    }
    __syncthreads();
    for (int cich=0; cich<4; cich++){
      #pragma unroll
      for (int j=0;j<10;j++){
        double wv0 = ws[cich*10+j][co_t     ];
        double wv1 = ws[cich*10+j][co_t + 16];
        double wv2 = ws[cich*10+j][co_t + 32];
        double wv3 = ws[cich*10+j][co_t + 48];
        #pragma unroll
        for (int m=0;m<4;m++){
          double xv = xs[cich][(lo_t + 16*m)*5 + j];
          acc[0][m] += wv0*xv; acc[1][m] += wv1*xv;
          acc[2][m] += wv2*xv; acc[3][m] += wv3*xv;
        }
      }
    }
  }
  #pragma unroll
  for (int c=0;c<4;c++){
    int co = co0 + co_t + 16*c;
    double bv  = (double)b1v[co];
    double a   = (double)a1v[co];
    double inv = 1.0/a;
    #pragma unroll
    for (int m=0;m<4;m++){
      int lo = lo0 + lo_t + 16*m;
      if (lo < 2999){
        double v = acc[c][m] + bv;
        double sn = sin(a*v);
        v = v + inv*sn*sn;
        out[((long)b*128 + co)*2999 + lo] = v;
      }
    }
  }
}

// ---------------- encoder conv E2/E3 (fp64 in, fp64 out) -------------------
template<int CIN,int COUT,int K,int S,int PAD,int CICH>
__global__ __launch_bounds__(256) void conv_enc(
    const double* __restrict__ x, const float* __restrict__ wp,
    const float* __restrict__ bias, const float* __restrict__ alpha,
    double* __restrict__ out, int Lin, int Lout)
{
  constexpr int WIDTH = 63*S + K;
  __shared__ double xs[CICH][WIDTH];
  __shared__ double ws[CICH*K][64];
  const int tid  = threadIdx.x;
  const int lo_t = tid & 15;
  const int co_t = tid >> 4;
  const int b    = blockIdx.z;
  const int co0  = blockIdx.y*64;
  const int lo0  = blockIdx.x*64;
  const int x0   = lo0*S - PAD;
  const long xb  = (long)b*CIN*Lin;
  double acc[4][4];
  #pragma unroll
  for (int c=0;c<4;c++){ acc[c][0]=0; acc[c][1]=0; acc[c][2]=0; acc[c][3]=0; }
  for (int ci0=0; ci0<CIN; ci0+=CICH){
    __syncthreads();
    for (int idx=tid; idx<CICH*WIDTH; idx+=256){
      int ci = idx / WIDTH, p = idx - ci*WIDTH;
      int g = x0 + p;
      xs[ci][p] = (g>=0 && g<Lin) ? x[xb + (long)(ci0+ci)*Lin + g] : 0.0;
    }
    for (int idx=tid; idx<CICH*K*64; idx+=256){
      int col = idx & 63, r = idx >> 6;
      ws[r][col] = (double)wp[(long)(ci0*K + r)*COUT + co0 + col];
    }
    __syncthreads();
    for (int ci=0; ci<CICH; ci++){
      #pragma unroll
      for (int j=0;j<K;j++){
        double w0 = ws[ci*K+j][co_t     ];
        double w1 = ws[ci*K+j][co_t + 16];
        double w2 = ws[ci*K+j][co_t + 32];
        double w3 = ws[ci*K+j][co_t + 48];
        #pragma unroll
        for (int m=0;m<4;m++){
          double xv = xs[ci][(lo_t + 16*m)*S + j];
          acc[0][m] += w0*xv; acc[1][m] += w1*xv;
          acc[2][m] += w2*xv; acc[3][m] += w3*xv;
        }
      }
    }
  }
  #pragma unroll
  for (int c=0;c<4;c++){
    int co = co0 + co_t + 16*c;
    double bv  = (double)bias[co];
    double a   = (double)alpha[co];
    double inv = 1.0/a;
    #pragma unroll
    for (int m=0;m<4;m++){
      int lo = lo0 + lo_t + 16*m;
      if (lo < Lout){
        double v = acc[c][m] + bv;
        double sn = sin(a*v);
        v = v + inv*sn*sn;
        out[((long)b*COUT + co)*Lout + lo] = v;
      }
    }
  }
}

// ---------------- decoder transposed conv, all-phases-per-block ------------
// Block computes 64co x 64t1 x ALL S phases. xs staged once per ci-chunk(32);
// weights staged per (r, chunk) (hot in L2). Output phase-major:
// out[((b*COUT+co)*S + r)*T1OUT + t1], lo = t1*S + r - PAD.
template<int CIN,int COUT,int K,int S,int PAD,
         int IMODE,int IS,int IT1,int IPAD,int T1OUT,int LOUT,typename OUTT>
__global__ __launch_bounds__(256) void convT_rm(
    const float* __restrict__ x, const float* __restrict__ wp,
    const float* __restrict__ bias, const float* __restrict__ alpha,
    OUTT* __restrict__ out, int Lin)
{
  __shared__ float xs[32][68];
  __shared__ float ws[32][2][64];
  const int tid  = threadIdx.x;
  const int lo_t = tid & 15;      // t1 = t10 + lo_t*4 + j
  const int co_t = tid >> 4;      // co = co0 + co_t*4 + c
  const int t10  = blockIdx.x*64;
  const int b    = blockIdx.z;
  const int co0  = blockIdx.y*64;
  float acc[S][16];
  #pragma unroll
  for (int r=0;r<S;r++)
    #pragma unroll
    for (int q=0;q<16;q++) acc[r][q] = 0.f;

  for (int ci0=0; ci0<CIN; ci0+=32){
    __syncthreads();
    for (int idx=tid; idx<32*65; idx+=256){
      int ci = idx / 65, p = idx - ci*65;
      int t = t10 - 1 + p;
      float v = 0.f;
      if (t >= 0 && t < Lin){
        long bci = (long)b*CIN + ci0 + ci;
        if (IMODE == 0) v = x[bci*Lin + t];
        else { int u = t + IPAD; int rr = u % IS; int tt = u / IS;
               v = x[(bci*IS + rr)*IT1 + tt]; }
      }
      xs[ci][p] = v;
    }
    #pragma unroll
    for (int r=0; r<S; r++){
      __syncthreads();
      for (int idx=tid; idx<32*2*64; idx+=256){
        int col = idx & 63, q = idx >> 6;
        int ci = q >> 1, tap = q & 1;
        ws[ci][tap][col] = wp[(long)((ci0+ci)*K + r + tap*S)*COUT + co0 + col];
      }
      __syncthreads();
      #pragma unroll 8
      for (int ci=0; ci<32; ci++){
        float4 wa = *(const float4*)&ws[ci][0][co_t*4];
        float4 wb = *(const float4*)&ws[ci][1][co_t*4];
        float4 xv = *(const float4*)&xs[ci][lo_t*4];
        float  xe = xs[ci][lo_t*4 + 4];
        float xp[5] = {xv.x, xv.y, xv.z, xv.w, xe};
        #pragma unroll
        for (int j=0;j<4;j++){
          float xa = xp[j+1];   // x[t1]
          float xb2 = xp[j];    // x[t1-1]
          acc[r][0*4+j] += wa.x*xa + wb.x*xb2;
          acc[r][1*4+j] += wa.y*xa + wb.y*xb2;
          acc[r][2*4+j] += wa.z*xa + wb.z*xb2;
          acc[r][3*4+j] += wa.w*xa + wb.w*xb2;
        }
      }
    }
  }

  const int t1b = t10 + lo_t*4;
  #pragma unroll
  for (int r=0; r<S; r++){
    #pragma unroll
    for (int c=0; c<4; c++){
      int co = co0 + co_t*4 + c;
      float bv  = bias[co];
      float a   = alpha[co];
      float inv = 1.f/a;
      long obase = ((long)((long)b*COUT + co)*S + r)*T1OUT;
      float v4[4];
      #pragma unroll
      for (int j=0;j<4;j++){
        float v = acc[r][c*4+j] + bv;
        float sn = __sinf(a*v);
        v4[j] = v + inv*sn*sn;
      }
      int lo0v = t1b*S + r - PAD;            // lo at j=0
      int lo3v = (t1b+3)*S + r - PAD;        // lo at j=3
      if (t1b + 3 < T1OUT && lo0v >= 0 && lo3v < LOUT){
        if constexpr (sizeof(OUTT) == 4){
          *(float4*)&((float*)out)[obase + t1b] = make_float4(v4[0],v4[1],v4[2],v4[3]);
        } else {
          __half2 h01(__float2half(v4[0]), __float2half(v4[1]));
          __half2 h23(__float2half(v4[2]), __float2half(v4[3]));
          *(__half2*)&((__half*)out)[obase + t1b    ] = h01;
          *(__half2*)&((__half*)out)[obase + t1b + 2] = h23;
        }
      } else {
        #pragma unroll
        for (int j=0;j<4;j++){
          int t1 = t1b + j;
          int lo = t1*S + r - PAD;
          if (t1 < T1OUT && lo >= 0 && lo < LOUT)
            out[obase + t1] = OUTT(v4[j]);
        }
      }
    }
  }
}

// ---------------- final decoder layer (reads D2 phase-major fp16) ----------
__global__ __launch_bounds__(256) void convT_last(
    const __half* __restrict__ x,  // pm [64][64][5][2993] fp16
    const float* __restrict__ w,   // [64][1][16]
    const float* __restrict__ bias,
    float* __restrict__ out)       // [64][119688]
{
  constexpr int LIN = 14961, LOUT = 119688, CIN = 64;
  __shared__ __align__(16) float xs[8][1028];
  __shared__ float ws[8][16];
  const int tid = threadIdx.x;
  const int b   = blockIdx.z;
  const int t10 = blockIdx.x*1024;
  float acc[4][8];
  #pragma unroll
  for (int u=0;u<4;u++) for (int rr=0;rr<8;rr++) acc[u][rr]=0.f;
  for (int ci0=0; ci0<CIN; ci0+=8){
    __syncthreads();
    for (int idx=tid; idx<8*1025; idx+=256){
      int ci = idx / 1025, p = idx - ci*1025;
      int t = t10 - 1 + p;
      float v = 0.f;
      if (t >= 0 && t < LIN){
        int u = t + 2; int rr = u % 5; int tt = u / 5;
        v = __half2float(x[((long)((long)b*CIN + ci0+ci)*5 + rr)*2993 + tt]);
      }
      xs[ci][p] = v;
    }
    if (tid < 128){
      int ci = tid >> 4, j = tid & 15;
      ws[ci][j] = w[(ci0+ci)*16 + j];
    }
    __syncthreads();
    #pragma unroll 2
    for (int ci=0; ci<8; ci++){
      float4 xv = *(const float4*)&xs[ci][tid*4];
      float  xe = xs[ci][tid*4 + 4];
      float xb_[5] = {xv.x, xv.y, xv.z, xv.w, xe};
      #pragma unroll
      for (int u=0;u<4;u++){
        float xprev = xb_[u];
        float xcur  = xb_[u+1];
        #pragma unroll
        for (int rr=0; rr<8; rr++)
          acc[u][rr] += ws[ci][rr]*xcur + ws[ci][rr+8]*xprev;
      }
    }
  }
  float bv = bias[0];
  #pragma unroll
  for (int u=0;u<4;u++){
    int t1 = t10 + tid*4 + u;
    #pragma unroll
    for (int rr=0;rr<8;rr++){
      int lo = t1*8 + rr - 4;
      if (lo >= 0 && lo < LOUT)
        out[(long)b*LOUT + lo] = tanhf(acc[u][rr] + bv);
    }
  }
}

// ======================= fp32 RVQ (tiled, bit-exact) =======================
__global__ void nv_transpose_f(const double* __restrict__ z, float* __restrict__ R){
  long i = (long)blockIdx.x*256 + threadIdx.x;     // ROWS*512
  if (i >= (long)ROWS*512) return;
  int row = (int)(i >> 9); int c = (int)(i & 511);
  int b = row / T_RVQ, t = row - b*T_RVQ;
  R[i] = (float)z[((long)b*512 + c)*T_RVQ + t];
}

__global__ __launch_bounds__(256) void rvq_proj_t(
    const float* __restrict__ R, const float* __restrict__ pin_w,
    const float* __restrict__ pin_b, float* __restrict__ zp)
{
  __shared__ float Rs[64][36];
  __shared__ float Ps[64][132];
  const int tid = threadIdx.x;
  const int row0 = blockIdx.x*32;
  const int d_t = tid & 31;       // d = d_t*4 + j
  const int r_t = tid >> 5;       // row = r_t*4 + k
  float acc[4][4];
  #pragma unroll
  for (int k=0;k<4;k++){ acc[k][0]=0; acc[k][1]=0; acc[k][2]=0; acc[k][3]=0; }
  for (int c0=0; c0<512; c0+=64){
    __syncthreads();
    for (int idx=tid; idx<2048; idx+=256){
      int c = idx & 63, r = idx >> 6;
      Rs[c][r] = R[(long)(row0+r)*512 + c0 + c];
    }
    for (int idx=tid; idx<8192; idx+=256){
      int c = idx & 63, d = idx >> 6;
      Ps[c][d] = pin_w[(long)d*512 + c0 + c];
    }
    __syncthreads();
    for (int c=0; c<64; c++){
      float4 rv = *(const float4*)&Rs[c][r_t*4];
      float4 wv = *(const float4*)&Ps[c][d_t*4];
      acc[0][0] += rv.x*wv.x; acc[0][1] += rv.x*wv.y; acc[0][2] += rv.x*wv.z; acc[0][3] += rv.x*wv.w;
      acc[1][0] += rv.y*wv.x; acc[1][1] += rv.y*wv.y; acc[1][2] += rv.y*wv.z; acc[1][3] += rv.y*wv.w;
      acc[2][0] += rv.z*wv.x; acc[2][1] += rv.z*wv.y; acc[2][2] += rv.z*wv.z; acc[2][3] += rv.z*wv.w;
      acc[3][0] += rv.w*wv.x; acc[3][1] += rv.w*wv.y; acc[3][2] += rv.w*wv.z; acc[3][3] += rv.w*wv.w;
    }
  }
  #pragma unroll
  for (int k=0;k<4;k++){
    int row = row0 + r_t*4 + k;
    #pragma unroll
    for (int j=0;j<4;j++){
      int d = d_t*4 + j;
      zp[(long)row*128 + d] = acc[k][j] + pin_b[d];
    }
  }
}

__global__ __launch_bounds__(256) void rvq_dist_t(
    const float* __restrict__ zp, const float* __restrict__ cb,
    const float* __restrict__ cn2, float* __restrict__ codes_out,
    int* __restrict__ codes_int, double* __restrict__ loss_acc, int book)
{
  __shared__ float zp_l[32][129];
  __shared__ float zp2_l[32];
  __shared__ float cb_s[32][132];
  __shared__ float cn2_s[128];
  __shared__ float sv[32][33];
  __shared__ int   si[32][33];
  __shared__ double ls[32];
  const int tid = threadIdx.x;
  const int row0 = blockIdx.x*32;
  const int n_t = tid & 31;       // code = tile*128 + n_t*4 + j
  const int r_t = tid >> 5;       // row  = r_t + 8*k
  for (int idx=tid; idx<32*128; idx+=256){
    int r = idx >> 7, d = idx & 127;
    zp_l[r][d] = zp[(long)(row0+r)*128 + d];
  }
  __syncthreads();
  if (tid < 32){
    float s2 = 0.f;
    for (int d=0; d<128; d++) s2 += zp_l[tid][d]*zp_l[tid][d];
    zp2_l[tid] = s2;
  }
  float best[4]; int bi[4];
  #pragma unroll
  for (int k=0;k<4;k++){ best[k]=3.4e38f; bi[k]=0; }
  for (int tile=0; tile<8; tile++){
    __syncthreads();
    if (tid < 128) cn2_s[tid] = cn2[tile*128 + tid];
    float dot[4][4];
    #pragma unroll
    for (int k=0;k<4;k++){ dot[k][0]=0; dot[k][1]=0; dot[k][2]=0; dot[k][3]=0; }
    for (int dch=0; dch<4; dch++){
      __syncthreads();
      for (int idx=tid; idx<128*32; idx+=256){
        int dd = idx & 31, n = idx >> 5;
        cb_s[dd][n] = cb[(long)(tile*128 + n)*128 + dch*32 + dd];
      }
      __syncthreads();
      for (int dd=0; dd<32; dd++){
        float4 cv = *(const float4*)&cb_s[dd][n_t*4];
        float zr[4];
        #pragma unroll
        for (int k=0;k<4;k++) zr[k] = zp_l[r_t + 8*k][dch*32 + dd];
        #pragma unroll
        for (int k=0;k<4;k++){
          dot[k][0] += zr[k]*cv.x; dot[k][1] += zr[k]*cv.y;
          dot[k][2] += zr[k]*cv.z; dot[k][3] += zr[k]*cv.w;
        }
      }
    }
    #pragma unroll
    for (int k=0;k<4;k++){
      float z2 = zp2_l[r_t + 8*k];
      #pragma unroll
      for (int j=0;j<4;j++){
        int n = n_t*4 + j;
        float dist = (z2 - 2.0f*dot[k][j]) + cn2_s[n];
        int gn = tile*128 + n;
        if (dist < best[k]){ best[k]=dist; bi[k]=gn; }
      }
    }
  }
  __syncthreads();
  #pragma unroll
  for (int k=0;k<4;k++){
    sv[r_t + 8*k][n_t] = best[k];
    si[r_t + 8*k][n_t] = bi[k];
  }
  __syncthreads();
  if (tid < 32){
    float b2 = sv[tid][0]; int i2 = si[tid][0];
    for (int q=1; q<32; q++){
      float v = sv[tid][q]; int ii = si[tid][q];
      if (v < b2 || (v == b2 && ii < i2)){ b2=v; i2=ii; }
    }
    int row = row0 + tid;
    int bb = row / T_RVQ, t = row - bb*T_RVQ;
    codes_out[bb*(NB*T_RVQ) + book*T_RVQ + t] = (float)i2;
    codes_int[(long)row*NB + book] = i2;
    ls[tid] = (double)b2;
  }
  __syncthreads();
  if (tid == 0){
    double s = 0.0;
    for (int rr=0;rr<32;rr++) s += ls[rr];
    atomicAdd(loss_acc, s);
  }
}

__global__ __launch_bounds__(256) void rvq_update_t(
    float* __restrict__ R, const float* __restrict__ cb,
    const float* __restrict__ zp, const float* __restrict__ pout_w,
    const float* __restrict__ pout_b, const int* __restrict__ codes_int,
    int book)
{
  __shared__ float st_l[32][128];
  __shared__ float po_s[64][132];
  __shared__ int code_l[32];
  const int tid = threadIdx.x;
  const int row0 = blockIdx.x*32;
  if (tid < 32) code_l[tid] = codes_int[(long)(row0+tid)*NB + book];
  __syncthreads();
  for (int idx=tid; idx<32*128; idx+=256){
    int r = idx >> 7, d = idx & 127;
    float zpv = zp[(long)(row0+r)*128 + d];
    float zqv = cb[(long)code_l[r]*128 + d];
    st_l[r][d] = zpv + (zqv - zpv);
  }
  const int r_t = tid >> 3;       // 0..31 row
  const int cl  = tid & 7;
  for (int c0=0; c0<512; c0+=64){
    __syncthreads();
    for (int idx=tid; idx<64*128; idx+=256){
      int d = idx & 127, c = idx >> 7;
      po_s[c][d] = pout_w[(long)(c0+c)*128 + d];
    }
    __syncthreads();
    float s[8];
    #pragma unroll
    for (int ii=0;ii<8;ii++) s[ii] = 0.f;
    for (int d4=0; d4<128; d4+=4){
      float4 sv4 = *(const float4*)&st_l[r_t][d4];
      #pragma unroll
      for (int ii=0; ii<8; ii++){
        float4 wv4 = *(const float4*)&po_s[cl + 8*ii][d4];
        s[ii] += sv4.x*wv4.x; s[ii] += sv4.y*wv4.y;
        s[ii] += sv4.z*wv4.z; s[ii] += sv4.w*wv4.w;
      }
    }
    #pragma unroll
    for (int ii=0; ii<8; ii++){
      int c = c0 + cl + 8*ii;
      long gi = (long)(row0 + r_t)*512 + c;
      R[gi] = R[gi] - (s[ii] + pout_b[c]);
    }
  }
}

__global__ void make_zq(const double* __restrict__ z, const float* __restrict__ R,
                        float* __restrict__ zq){
  long i = (long)blockIdx.x*256 + threadIdx.x;     // ROWS*512
  if (i >= (long)ROWS*512) return;
  int row = (int)(i >> 9); int c = (int)(i & 511);
  int b = row / T_RVQ, t = row - b*T_RVQ;
  long zi = ((long)b*512 + c)*T_RVQ + t;
  zq[zi] = (float)z[zi] - R[i];
}

__global__ void loss_final(const double* __restrict__ loss_acc, float* __restrict__ out){
  out[0] = (float)(loss_acc[0] * (1.25 / 2039808.0));   // 1.25/(64*249*128)
}

// ---------------------------------------------------------------------------
extern "C" void kernel_launch(void* const* d_in, const int* in_sizes, int n_in,
                              void* d_out, int out_size, void* d_ws, size_t ws_size,
                              hipStream_t stream)
{
  (void)in_sizes; (void)n_in; (void)out_size; (void)ws_size;
  const float* audio  = (const float*)d_in[0];
  const float* ew0=(const float*)d_in[1],  *eb0=(const float*)d_in[2],  *ea0=(const float*)d_in[3];
  const float* ew1=(const float*)d_in[4],  *eb1=(const float*)d_in[5],  *ea1=(const float*)d_in[6];
  const float* ew2=(const float*)d_in[7],  *eb2=(const float*)d_in[8],  *ea2=(const float*)d_in[9];
  const float* ew3=(const float*)d_in[10], *eb3=(const float*)d_in[11], *ea3=(const float*)d_in[12];
  const float* dw0=(const float*)d_in[13], *db0=(const float*)d_in[14], *da0=(const float*)d_in[15];
  const float* dw1=(const float*)d_in[16], *db1=(const float*)d_in[17], *da1=(const float*)d_in[18];
  const float* dw2=(const float*)d_in[19], *db2=(const float*)d_in[20], *da2=(const float*)d_in[21];
  const float* dw3=(const float*)d_in[22], *db3=(const float*)d_in[23];
  const float* pin_w =(const float*)d_in[24], *pin_b =(const float*)d_in[25];
  const float* pout_w=(const float*)d_in[26], *pout_b=(const float*)d_in[27];
  const float* cbs   =(const float*)d_in[28];

  float* out_audio = (float*)d_out;                 // 64*119688 = 7660032
  float* out_codes = out_audio + 7660032;           // 64*8*249  = 127488
  float* out_loss  = out_audio + 7787520;           // 1

  // ---- workspace layout (peak ~230.5 MB, lifetime-aliased) ----
  char* base = (char*)d_ws;
  double* z64    = (double*)(base);                 // [64][512][249] f64 (65,273,856)
  double* e1half = (double*)(base +  65273856);     // [32][128][2999] f64
  double* e2half = (double*)(base + 163545088);     // [32][256][749]  f64 ends 212,631,552
  float*  R      = (float*) (base +  65273856);     // [15936][512] ends 97,910,784
  float*  zp_f   = (float*) (base +  97910784);     // [15936][128] ends 106,070,400
  float*  zq32   = (float*) (base + 106070400);     // [64][512][249] ends 138,707,328
  float*  d0pm   = (float*) (base);                 // [64][256][3][250] 49,152,000 (z64 dead)
  float*  d1pm   = (float*) (base + 122683392);     // [64][128][4][749] ends 220,856,320
  __half* d2pm   = (__half*)(base);                 // [64][64][5][2993] 122,593,280
  char* p = base + 220856320;
  auto alloc = [&](size_t bytes)->char*{
    char* r = p; p += (bytes + 255) & ~(size_t)255; return r;
  };
  float* wpE1 = (float*)alloc((size_t)128*64*10*4);
  float* wpE2 = (float*)alloc((size_t)256*128*8*4);
  float* wpE3 = (float*)alloc((size_t)512*256*6*4);
  float* wpD0 = (float*)alloc((size_t)512*256*6*4);
  float* wpD1 = (float*)alloc((size_t)256*128*8*4);
  float* wpD2 = (float*)alloc((size_t)128*64*10*4);
  float* cn2f = (float*)alloc((size_t)NB*NCODE*4);
  int* codesI = (int*)  alloc((size_t)ROWS*NB*4);
  double* lossA=(double*)alloc(256);

  // ---- packing / precompute ----
  pack_w_conv <<<cdiv(128*64*10,256),256,0,stream>>>(ew1, wpE1, 128, 64, 10);
  pack_w_conv <<<cdiv(256*128*8,256),256,0,stream>>>(ew2, wpE2, 256, 128, 8);
  pack_w_conv <<<cdiv(512*256*6,256),256,0,stream>>>(ew3, wpE3, 512, 256, 6);
  pack_w_convT<<<cdiv(512*256*6,256),256,0,stream>>>(dw0, wpD0, 512, 256, 6);
  pack_w_convT<<<cdiv(256*128*8,256),256,0,stream>>>(dw1, wpD1, 256, 128, 8);
  pack_w_convT<<<cdiv(128*64*10,256),256,0,stream>>>(dw2, wpD2, 128, 64, 10);
  prep_cn2f  <<<cdiv(NB*NCODE,256),256,0,stream>>>(cbs, cn2f);
  zero_loss  <<<1,1,0,stream>>>(lossA);

  // ---- encoder (E0 fused into E1; fp64; two batch halves) ----
  for (int h=0; h<2; h++){
    long b0 = 32L*h;
    conv_e0e1<<<dim3(cdiv(2999,64),2,32),256,0,stream>>>(
        audio + b0*120000, ew0, eb0, ea0, wpE1, eb1, ea1, e1half);
    conv_enc<128,256,8,4,2,8> <<<dim3(cdiv(749,64),4,32),256,0,stream>>>(
        e1half, wpE2, eb2, ea2, e2half, 2999, 749);
    conv_enc<256,512,6,3,1,8> <<<dim3(cdiv(249,64),8,32),256,0,stream>>>(
        e2half, wpE3, eb3, ea3, z64 + b0*512*249, 749, 249);
  }

  // ---- fp32 RVQ (tiled; bit-exact arithmetic order) ----
  nv_transpose_f<<<cdiv(ROWS*512,256),256,0,stream>>>(z64, R);
  for (int bk=0; bk<NB; bk++){
    rvq_proj_t<<<ROWS/32,256,0,stream>>>(R, pin_w, pin_b, zp_f);
    rvq_dist_t<<<ROWS/32,256,0,stream>>>(zp_f, cbs + (long)bk*NCODE*128,
                                         cn2f + bk*NCODE, out_codes, codesI, lossA, bk);
    rvq_update_t<<<ROWS/32,256,0,stream>>>(R, cbs + (long)bk*NCODE*128, zp_f,
                                           pout_w, pout_b, codesI, bk);
  }
  make_zq<<<cdiv(ROWS*512,256),256,0,stream>>>(z64, R, zq32);

  // ---- decoder (all-phases-per-block, phase-major intermediates) ----
  convT_rm<512,256,6,3,1, 0,1,1,0, 250, 748, float>
      <<<dim3(cdiv(250,64), 4, 64),256,0,stream>>>(zq32, wpD0, db0, da0, d0pm, 249);
  convT_rm<256,128,8,4,2, 1,3,250,1, 749, 2992, float>
      <<<dim3(cdiv(749,64), 2, 64),256,0,stream>>>(d0pm, wpD1, db1, da1, d1pm, 748);
  convT_rm<128,64,10,5,2, 1,4,749,2, 2993, 14961, __half>
      <<<dim3(cdiv(2993,64), 1, 64),256,0,stream>>>(d1pm, wpD2, db2, da2, d2pm, 2992);
  convT_last<<<dim3(cdiv(14962,1024),1,64),256,0,stream>>>(d2pm, dw3, db3, out_audio);

  loss_final<<<1,1,0,stream>>>(lossA, out_loss);
}